// Round 4
// baseline (4539.890 us; speedup 1.0000x reference)
//
#include <hip/hip_runtime.h>
#include <hip/hip_bf16.h>
#include <math.h>

#define BATCH 8192
#define INSZ 784
#define SYS 1024
#define OUTSZ 10
#define NSTEP 100
#define HSTEP 0.01f
#define FFORCE 8.0f
#define KP 800   // 25*32: K padded for pre-split arrays (784..799 zero-filled)

typedef short short8 __attribute__((ext_vector_type(8)));
typedef float float4v __attribute__((ext_vector_type(4)));

static __device__ __forceinline__ short f2bf(float x) {
    __hip_bfloat16 b = __float2bfloat16(x);   // RNE
    return __builtin_bit_cast(short, b);
}
static __device__ __forceinline__ float bf2f(short s) {
    unsigned int u = ((unsigned int)(unsigned short)s) << 16;
    return __builtin_bit_cast(float, u);
}

// 16B global -> LDS DMA (vmcnt-tracked; drains at __syncthreads)
static __device__ __forceinline__ void gld_lds16(const void* g, void* l) {
    __builtin_amdgcn_global_load_lds(
        (const __attribute__((address_space(1))) unsigned int*)g,
        (__attribute__((address_space(3))) unsigned int*)l, 16, 0, 0);
}

// ---------------------------------------------------------------------------
// convert_kernel: one-shot fp32 -> split-bf16 (hi + lo residual, RNE).
// Bit-identical to the in-gemm conversion (absmax 0.03125 all rounds).
// ---------------------------------------------------------------------------
__global__ __launch_bounds__(256) void convert_kernel(
    const float* __restrict__ x, const float* __restrict__ W1,
    short* __restrict__ xh, short* __restrict__ xl,
    short* __restrict__ wh, short* __restrict__ wl)
{
    const int total = (BATCH + SYS) * (KP / 8);   // 921600 8-elem chunks
    for (int idx = blockIdx.x * blockDim.x + threadIdx.x; idx < total;
         idx += gridDim.x * blockDim.x) {
        const int row = idx / (KP / 8);
        const int ck  = idx - row * (KP / 8);

        short8 hi, lo;
        if (ck < INSZ / 8) {
            const float* src = (row < BATCH)
                ? (x + (size_t)row * INSZ)
                : (W1 + (size_t)(row - BATCH) * INSZ);
            float4 v0 = ((const float4*)src)[ck * 2];
            float4 v1 = ((const float4*)src)[ck * 2 + 1];
            float vv[8] = {v0.x, v0.y, v0.z, v0.w, v1.x, v1.y, v1.z, v1.w};
            #pragma unroll
            for (int j = 0; j < 8; ++j) {
                short hj = f2bf(vv[j]);
                hi[j] = hj;
                lo[j] = f2bf(vv[j] - bf2f(hj));
            }
        } else {
            #pragma unroll
            for (int j = 0; j < 8; ++j) { hi[j] = 0; lo[j] = 0; }
        }

        short* dh; short* dl;
        if (row < BATCH) {
            dh = xh + (size_t)row * KP;
            dl = xl + (size_t)row * KP;
        } else {
            dh = wh + (size_t)(row - BATCH) * KP;
            dl = wl + (size_t)(row - BATCH) * KP;
        }
        *(short8*)(dh + ck * 8) = hi;
        *(short8*)(dl + ck * 8) = lo;
    }
}

// ---------------------------------------------------------------------------
// GEMM1 v3 (unchanged from r3): 128x128 / BK=32, global_load_lds staging,
// XCD-chunked swizzle. Held constant this round to isolate the rk4 change.
// ---------------------------------------------------------------------------
#define BM3 128
#define BN3 128
#define BK3 32

__global__ __launch_bounds__(512, 4) void gemm1s_kernel(
    const short* __restrict__ xh, const short* __restrict__ xl,
    const short* __restrict__ wh, const short* __restrict__ wl,
    const float* __restrict__ b1, float* __restrict__ h)
{
    __shared__ short Ah[BM3 * BK3], Al[BM3 * BK3];
    __shared__ short Bh[BN3 * BK3], Bl[BN3 * BK3];   // 4 * 8 KB = 32 KB

    const int t = threadIdx.x;            // 0..511

    const int lin = blockIdx.y * gridDim.x + blockIdx.x;   // 0..511
    const int nwg = gridDim.x * gridDim.y;                 // 512
    const int cpx = nwg >> 3;                              // 64
    const int swz = (lin & 7) * cpx + (lin >> 3);
    const int bm  = (swz >> 3) * BM3;
    const int bn  = (swz & 7) * BN3;

    const int srow = t >> 2;              // 0..127
    const int wv   = t >> 6;              // 0..7
    const int lane = t & 63;

    const int wr   = wv >> 1;             // 0..3
    const int wc   = wv & 1;              // 0..1
    const int lm   = lane & 15;
    const int q    = lane >> 4;

    float4v acc[2][4];
    #pragma unroll
    for (int mi = 0; mi < 2; ++mi)
        #pragma unroll
        for (int nj = 0; nj < 4; ++nj) {
            acc[mi][nj][0] = 0.f; acc[mi][nj][1] = 0.f;
            acc[mi][nj][2] = 0.f; acc[mi][nj][3] = 0.f;
        }

    const short* gxh = xh + (size_t)(bm + srow) * KP + (t & 3) * 8;
    const short* gxl = xl + (size_t)(bm + srow) * KP + (t & 3) * 8;
    const short* gwh = wh + (size_t)(bn + srow) * KP + (t & 3) * 8;
    const short* gwl = wl + (size_t)(bn + srow) * KP + (t & 3) * 8;

    short* lAh = &Ah[wv * 512];
    short* lAl = &Al[wv * 512];
    short* lBh = &Bh[wv * 512];
    short* lBl = &Bl[wv * 512];

    gld_lds16(gxh, lAh);
    gld_lds16(gxl, lAl);
    gld_lds16(gwh, lBh);
    gld_lds16(gwl, lBl);

    for (int it = 0; it < 25; ++it) {
        __syncthreads();

        short8 fah[2], fal[2], fbh[4], fbl[4];
        #pragma unroll
        for (int mi = 0; mi < 2; ++mi) {
            const int ao = (wr * 32 + mi * 16 + lm) * BK3 + q * 8;
            fah[mi] = *(const short8*)&Ah[ao];
            fal[mi] = *(const short8*)&Al[ao];
        }
        #pragma unroll
        for (int nj = 0; nj < 4; ++nj) {
            const int bo = (wc * 64 + nj * 16 + lm) * BK3 + q * 8;
            fbh[nj] = *(const short8*)&Bh[bo];
            fbl[nj] = *(const short8*)&Bl[bo];
        }
        __syncthreads();

        if (it < 24) {
            const int k1 = (it + 1) * BK3;
            gld_lds16(gxh + k1, lAh);
            gld_lds16(gxl + k1, lAl);
            gld_lds16(gwh + k1, lBh);
            gld_lds16(gwl + k1, lBl);
        }

        #pragma unroll
        for (int nj = 0; nj < 4; ++nj) {
            #pragma unroll
            for (int mi = 0; mi < 2; ++mi) {
                acc[mi][nj] = __builtin_amdgcn_mfma_f32_16x16x32_bf16(fah[mi], fbh[nj], acc[mi][nj], 0, 0, 0);
                acc[mi][nj] = __builtin_amdgcn_mfma_f32_16x16x32_bf16(fah[mi], fbl[nj], acc[mi][nj], 0, 0, 0);
                acc[mi][nj] = __builtin_amdgcn_mfma_f32_16x16x32_bf16(fal[mi], fbh[nj], acc[mi][nj], 0, 0, 0);
            }
        }
    }

    #pragma unroll
    for (int mi = 0; mi < 2; ++mi) {
        const int row0 = bm + wr * 32 + mi * 16 + q * 4;
        #pragma unroll
        for (int nj = 0; nj < 4; ++nj) {
            const int col  = bn + wc * 64 + nj * 16 + lm;
            const float bias = b1[col];
            #pragma unroll
            for (int r = 0; r < 4; ++r)
                h[(size_t)(row0 + r) * SYS + col] = acc[mi][nj][r] + bias;
        }
    }
}

// ---------------------------------------------------------------------------
// GEMM1 fallback (in-kernel conversion, 64x64) — only if workspace too small.
// ---------------------------------------------------------------------------
#define BM2 64
#define BN2 64
#define BK2 32
#define LDK2 40

__global__ __launch_bounds__(256, 4) void gemm1_kernel(
    const float* __restrict__ x, const float* __restrict__ W1,
    const float* __restrict__ b1, float* __restrict__ h)
{
    __shared__ short Ah[BM2 * LDK2], Al[BM2 * LDK2];
    __shared__ short Bh[BN2 * LDK2], Bl[BN2 * LDK2];

    const int t  = threadIdx.x;
    const int bm = blockIdx.y * BM2;
    const int bn = blockIdx.x * BN2;

    const int srow = t >> 2;
    const int kq   = (t & 3) * 8;

    const int wv   = t >> 6;
    const int lane = t & 63;
    const int lm   = lane & 15;
    const int q    = lane >> 4;

    float4v acc[4];
    #pragma unroll
    for (int j = 0; j < 4; ++j) {
        acc[j][0] = 0.f; acc[j][1] = 0.f; acc[j][2] = 0.f; acc[j][3] = 0.f;
    }

    const float* xa0 = x  + (size_t)(bm + srow) * INSZ + kq;
    const float* wb0 = W1 + (size_t)(bn + srow) * INSZ + kq;

    for (int it = 0; it < 25; ++it) {
        const int k0 = it * BK2;
        {
            const bool valid = (k0 + kq) < INSZ;
            float va[8], vb[8];
            if (valid) {
                #pragma unroll
                for (int p = 0; p < 2; ++p) {
                    float4 xv = ((const float4*)(xa0 + k0))[p];
                    float4 bv = ((const float4*)(wb0 + k0))[p];
                    va[4*p+0] = xv.x; va[4*p+1] = xv.y; va[4*p+2] = xv.z; va[4*p+3] = xv.w;
                    vb[4*p+0] = bv.x; vb[4*p+1] = bv.y; vb[4*p+2] = bv.z; vb[4*p+3] = bv.w;
                }
            } else {
                #pragma unroll
                for (int j = 0; j < 8; ++j) { va[j] = 0.f; vb[j] = 0.f; }
            }
            short8 ahi, alo, bhi, blo;
            #pragma unroll
            for (int j = 0; j < 8; ++j) {
                short h1 = f2bf(va[j]);
                short l1 = f2bf(va[j] - bf2f(h1));
                short h2 = f2bf(vb[j]);
                short l2 = f2bf(vb[j] - bf2f(h2));
                ahi[j] = h1;  alo[j] = l1;
                bhi[j] = h2;  blo[j] = l2;
            }
            const int base = srow * LDK2 + kq;
            *(short8*)&Ah[base] = ahi;
            *(short8*)&Al[base] = alo;
            *(short8*)&Bh[base] = bhi;
            *(short8*)&Bl[base] = blo;
        }
        __syncthreads();

        const int aoff = (wv * 16 + lm) * LDK2 + q * 8;
        short8 ah = *(const short8*)&Ah[aoff];
        short8 al = *(const short8*)&Al[aoff];
        #pragma unroll
        for (int fj = 0; fj < 4; ++fj) {
            const int boff = (fj * 16 + lm) * LDK2 + q * 8;
            short8 bh = *(const short8*)&Bh[boff];
            short8 bl = *(const short8*)&Bl[boff];
            acc[fj] = __builtin_amdgcn_mfma_f32_16x16x32_bf16(ah, bh, acc[fj], 0, 0, 0);
            acc[fj] = __builtin_amdgcn_mfma_f32_16x16x32_bf16(ah, bl, acc[fj], 0, 0, 0);
            acc[fj] = __builtin_amdgcn_mfma_f32_16x16x32_bf16(al, bh, acc[fj], 0, 0, 0);
        }
        __syncthreads();
    }

    #pragma unroll
    for (int fj = 0; fj < 4; ++fj) {
        const int col  = bn + fj * 16 + lm;
        const float bias = b1[col];
        const int row0 = bm + wv * 16 + q * 4;
        #pragma unroll
        for (int r = 0; r < 4; ++r)
            h[(size_t)(row0 + r) * SYS + col] = acc[fj][r] + bias;
    }
}

// ---------------------------------------------------------------------------
// RK4 Lorenz-96 + GEMM2 + log_softmax — SCALAR 1-row-per-wave rewrite.
// r3 audit: v2f version had 96 VGPR of live state but VGPR_Count=64 ->
// compiler parked ~32 values in AGPRs (accvgpr_read/write on every access,
// pure overhead), and packed f32 has no issue-rate benefit on CDNA4
// (157.3 TF spec = 1 scalar FMA/lane/cyc). Scalar 1-row/wave:
//   - state 48 f32 + temps ~= 60 VGPR, fits 64 natively (no AGPR traffic)
//   - 8192 waves (2x) -> 8 waves/SIMD: covers bpermute latency + gaps
//   - identical per-element op order -> bit-identical output
// ---------------------------------------------------------------------------
__global__ __launch_bounds__(256, 8) void rk4_kernel(
    const float* __restrict__ hbuf, const float* __restrict__ W2,
    const float* __restrict__ b2, float* __restrict__ out)
{
    const int lane = threadIdx.x & 63;
    const int w    = threadIdx.x >> 6;
    const int row  = blockIdx.x * 4 + w;      // 2048 blocks x 4 waves

    const int laneL = (lane + 63) & 63;
    const int laneR = (lane + 1) & 63;

    float X[16];
    {
        const float4* a4 = (const float4*)(hbuf + (size_t)row * SYS) + lane * 4;
        #pragma unroll
        for (int k = 0; k < 4; ++k) {
            float4 av = a4[k];
            X[4*k+0] = av.x; X[4*k+1] = av.y; X[4*k+2] = av.z; X[4*k+3] = av.w;
        }
    }

    const float c_half = 0.5f * HSTEP;
    const float c_six  = HSTEP / 6.0f;

    float acc[16], T[16];

    // in-place deriv with pre-issued halos; interior first, DS consumers last
    auto deriv_ip = [&](float (&y)[16], float r1, float l1, float l2) {
        float y0o = y[0], y1o = y[1], y2o = y[2];
        float d0 = FFORCE - y[0], d1 = FFORCE - y[1], d15 = FFORCE - y[15];
        float p2 = y0o, p1 = y1o, cur = y[2];
        #pragma unroll
        for (int i = 2; i < 15; ++i) {
            float yp1 = (i < 14) ? y[i + 1] : y[15];
            float nv  = fmaf(yp1 - p2, p1, FFORCE - cur);
            p2 = p1; p1 = cur;
            if (i < 14) cur = y[i + 1];
            y[i] = nv;
        }
        y[15] = fmaf(r1 - p2, p1, d15);      // first DS consume
        y[1]  = fmaf(y2o - l1, y0o, d1);
        y[0]  = fmaf(y1o - l2, l1, d0);
    };

    // k1 halos on X
    float r1x = __shfl(X[0],  laneR);
    float l1x = __shfl(X[15], laneL);
    float l2x = __shfl(X[14], laneL);

    #pragma unroll 1
    for (int s = 0; s < NSTEP; ++s) {
        // ---- k1 = deriv(X) out-of-place into acc (X intact) ----
        #pragma unroll
        for (int i = 2; i < 15; ++i)
            acc[i] = fmaf(X[i + 1] - X[i - 2], X[i - 1], FFORCE - X[i]);
        acc[15] = fmaf(r1x - X[13], X[14], FFORCE - X[15]);
        acc[1]  = fmaf(X[2] - l1x, X[0],  FFORCE - X[1]);
        acc[0]  = fmaf(X[1] - l2x, l1x,   FFORCE - X[0]);

        // ---- T = X + h/2 * k1 ; boundary first, issue k2 halos ----
        T[14] = fmaf(c_half, acc[14], X[14]);
        T[15] = fmaf(c_half, acc[15], X[15]);
        T[0]  = fmaf(c_half, acc[0],  X[0]);
        float r1 = __shfl(T[0],  laneR);
        float l1 = __shfl(T[15], laneL);
        float l2 = __shfl(T[14], laneL);
        #pragma unroll
        for (int i = 1; i < 14; ++i) T[i] = fmaf(c_half, acc[i], X[i]);
        deriv_ip(T, r1, l1, l2);                        // T = k2

        // ---- acc += 2*k2 ; T = X + h/2*k2 ; boundary first, k3 halos ----
        {
            float a;
            a = T[14]; acc[14] = fmaf(2.0f, a, acc[14]); T[14] = fmaf(c_half, a, X[14]);
            a = T[15]; acc[15] = fmaf(2.0f, a, acc[15]); T[15] = fmaf(c_half, a, X[15]);
            a = T[0];  acc[0]  = fmaf(2.0f, a, acc[0]);  T[0]  = fmaf(c_half, a, X[0]);
            r1 = __shfl(T[0],  laneR);
            l1 = __shfl(T[15], laneL);
            l2 = __shfl(T[14], laneL);
            #pragma unroll
            for (int i = 1; i < 14; ++i) {
                a = T[i]; acc[i] = fmaf(2.0f, a, acc[i]); T[i] = fmaf(c_half, a, X[i]);
            }
        }
        deriv_ip(T, r1, l1, l2);                        // T = k3

        // ---- acc += 2*k3 ; T = X + h*k3 ; boundary first, k4 halos ----
        {
            float a;
            a = T[14]; acc[14] = fmaf(2.0f, a, acc[14]); T[14] = fmaf(HSTEP, a, X[14]);
            a = T[15]; acc[15] = fmaf(2.0f, a, acc[15]); T[15] = fmaf(HSTEP, a, X[15]);
            a = T[0];  acc[0]  = fmaf(2.0f, a, acc[0]);  T[0]  = fmaf(HSTEP, a, X[0]);
            r1 = __shfl(T[0],  laneR);
            l1 = __shfl(T[15], laneL);
            l2 = __shfl(T[14], laneL);
            #pragma unroll
            for (int i = 1; i < 14; ++i) {
                a = T[i]; acc[i] = fmaf(2.0f, a, acc[i]); T[i] = fmaf(HSTEP, a, X[i]);
            }
        }
        deriv_ip(T, r1, l1, l2);                        // T = k4

        // ---- X += h/6 * (acc + k4) ; boundary first, next k1 halos ----
        X[14] = fmaf(c_six, acc[14] + T[14], X[14]);
        X[15] = fmaf(c_six, acc[15] + T[15], X[15]);
        X[0]  = fmaf(c_six, acc[0]  + T[0],  X[0]);
        r1x = __shfl(X[0],  laneR);
        l1x = __shfl(X[15], laneL);
        l2x = __shfl(X[14], laneL);
        #pragma unroll
        for (int i = 1; i < 14; ++i)
            X[i] = fmaf(c_six, acc[i] + T[i], X[i]);
    }

    // GEMM2 + log_softmax for this row
    float l[OUTSZ];
    #pragma unroll
    for (int o = 0; o < OUTSZ; ++o) {
        const float4* w4 = (const float4*)(W2 + (size_t)o * SYS) + lane * 4;
        float s2 = 0.f;
        #pragma unroll
        for (int k = 0; k < 4; ++k) {
            float4 wv = w4[k];
            s2 = fmaf(X[4*k+0], wv.x, s2);
            s2 = fmaf(X[4*k+1], wv.y, s2);
            s2 = fmaf(X[4*k+2], wv.z, s2);
            s2 = fmaf(X[4*k+3], wv.w, s2);
        }
        #pragma unroll
        for (int dlt = 1; dlt < 64; dlt <<= 1)
            s2 += __shfl_xor(s2, dlt);
        l[o] = s2 + b2[o];
    }

    float m = l[0];
    #pragma unroll
    for (int o = 1; o < OUTSZ; ++o) m = fmaxf(m, l[o]);
    float ssum = 0.f;
    #pragma unroll
    for (int o = 0; o < OUTSZ; ++o) ssum += __expf(l[o] - m);
    const float lse = m + __logf(ssum);

    float vA = l[0] - lse;
    #pragma unroll
    for (int o = 1; o < OUTSZ; ++o) {
        if (lane == o) vA = l[o] - lse;
    }
    if (lane < OUTSZ)
        out[(size_t)row * OUTSZ + lane] = vA;
}

extern "C" void kernel_launch(void* const* d_in, const int* in_sizes, int n_in,
                              void* d_out, int out_size, void* d_ws, size_t ws_size,
                              hipStream_t stream)
{
    const float* x  = (const float*)d_in[0];
    const float* W1 = (const float*)d_in[1];
    const float* b1 = (const float*)d_in[2];
    const float* W2 = (const float*)d_in[3];
    const float* b2 = (const float*)d_in[4];
    float* out = (float*)d_out;
    float* h   = (float*)d_ws;   // 8192*1024*4 = 33.5 MB scratch

    const size_t hbytes      = (size_t)BATCH * SYS * sizeof(float);
    const size_t splitshorts = (size_t)(BATCH + SYS) * KP;           // per hi/lo member
    const size_t need        = hbytes + 2 * splitshorts * sizeof(short);

    if (ws_size >= need) {
        short* xh = (short*)((char*)d_ws + hbytes);
        short* xl = xh + (size_t)BATCH * KP;
        short* wh = xl + (size_t)BATCH * KP;
        short* wl = wh + (size_t)SYS * KP;
        convert_kernel<<<2048, 256, 0, stream>>>(x, W1, xh, xl, wh, wl);
        dim3 g1(SYS / BN3, BATCH / BM3);   // 8 x 64 = 512 blocks, 512 threads
        gemm1s_kernel<<<g1, 512, 0, stream>>>(xh, xl, wh, wl, b1, h);
    } else {
        dim3 g1(SYS / BN2, BATCH / BM2);   // fallback: 16 x 128 = 2048 blocks
        gemm1_kernel<<<g1, 256, 0, stream>>>(x, W1, b1, h);
    }

    rk4_kernel<<<BATCH / 4, 256, 0, stream>>>(h, W2, b2, out);  // 2048 blocks, 1 row/wave
}

// Round 5
// 395.882 us; speedup vs baseline: 11.4678x; 11.4678x over previous
//
#include <hip/hip_runtime.h>
#include <hip/hip_bf16.h>
#include <math.h>

#define BATCH 8192
#define INSZ 784
#define SYS 1024
#define OUTSZ 10
#define NSTEP 100
#define HSTEP 0.01f
#define FFORCE 8.0f
#define KP 800   // 25*32: K padded for pre-split arrays (784..799 zero-filled)

typedef short short8 __attribute__((ext_vector_type(8)));
typedef float float4v __attribute__((ext_vector_type(4)));
typedef float v2f __attribute__((ext_vector_type(2)));

static __device__ __forceinline__ short f2bf(float x) {
    __hip_bfloat16 b = __float2bfloat16(x);   // RNE
    return __builtin_bit_cast(short, b);
}
static __device__ __forceinline__ float bf2f(short s) {
    unsigned int u = ((unsigned int)(unsigned short)s) << 16;
    return __builtin_bit_cast(float, u);
}

static __device__ __forceinline__ v2f pkfma(v2f a, v2f b, v2f c) {
    return __builtin_elementwise_fma(a, b, c);
}
static __device__ __forceinline__ v2f mk2(float x, float y) {
    v2f r; r.x = x; r.y = y; return r;
}
// halo transport on the DS pipe (overlaps with VALU; DPP regressed — r5)
static __device__ __forceinline__ v2f sh2(v2f v, int ln) {
    v2f r; r.x = __shfl(v.x, ln); r.y = __shfl(v.y, ln); return r;
}

// 16B global -> LDS DMA (vmcnt-tracked; drains at __syncthreads)
static __device__ __forceinline__ void gld_lds16(const void* g, void* l) {
    __builtin_amdgcn_global_load_lds(
        (const __attribute__((address_space(1))) unsigned int*)g,
        (__attribute__((address_space(3))) unsigned int*)l, 16, 0, 0);
}

// ---------------------------------------------------------------------------
// convert_kernel: one-shot fp32 -> split-bf16 (hi + lo residual, RNE).
// Bit-identical to the in-gemm conversion (absmax 0.03125 all rounds).
// ---------------------------------------------------------------------------
__global__ __launch_bounds__(256) void convert_kernel(
    const float* __restrict__ x, const float* __restrict__ W1,
    short* __restrict__ xh, short* __restrict__ xl,
    short* __restrict__ wh, short* __restrict__ wl)
{
    const int total = (BATCH + SYS) * (KP / 8);   // 921600 8-elem chunks
    for (int idx = blockIdx.x * blockDim.x + threadIdx.x; idx < total;
         idx += gridDim.x * blockDim.x) {
        const int row = idx / (KP / 8);
        const int ck  = idx - row * (KP / 8);

        short8 hi, lo;
        if (ck < INSZ / 8) {
            const float* src = (row < BATCH)
                ? (x + (size_t)row * INSZ)
                : (W1 + (size_t)(row - BATCH) * INSZ);
            float4 v0 = ((const float4*)src)[ck * 2];
            float4 v1 = ((const float4*)src)[ck * 2 + 1];
            float vv[8] = {v0.x, v0.y, v0.z, v0.w, v1.x, v1.y, v1.z, v1.w};
            #pragma unroll
            for (int j = 0; j < 8; ++j) {
                short hj = f2bf(vv[j]);
                hi[j] = hj;
                lo[j] = f2bf(vv[j] - bf2f(hj));
            }
        } else {
            #pragma unroll
            for (int j = 0; j < 8; ++j) { hi[j] = 0; lo[j] = 0; }
        }

        short* dh; short* dl;
        if (row < BATCH) {
            dh = xh + (size_t)row * KP;
            dl = xl + (size_t)row * KP;
        } else {
            dh = wh + (size_t)(row - BATCH) * KP;
            dl = wl + (size_t)(row - BATCH) * KP;
        }
        *(short8*)(dh + ck * 8) = hi;
        *(short8*)(dl + ck * 8) = lo;
    }
}

// ---------------------------------------------------------------------------
// GEMM1 v4: h = x @ W1^T + b1. BM=128 x BN=256, BK=32, global_load_lds DMA.
// r3 post-mortem (DMA-supply model): phase time tracks aggregate global
// traffic: r3 = 26.2MB*(1024/BN) + 3.3MB*(8192/BM) = 420 MB. This tile:
//   x re-reads 8x -> 4x (210 -> 105 MB)
//   W term (210 MB of re-reads) becomes L2-RESIDENT: wh+wl = 3.3 MB < 4 MB
//     per-XCD L2 -> refills at 34.5 TB/s, not HBM/L3 rate
//   48 MFMA per 16 ds_read_b128 per wave-iter (2x better than r3)
//   grid stays 256 blocks (every CU busy), swizzle groups the 4 same-x-panel
//     blocks onto one XCD back-to-back for x L2 reuse.
// ---------------------------------------------------------------------------
#define BM4 128
#define BN4 256
#define BK4 32

__global__ __launch_bounds__(512, 4) void gemm1s_kernel(
    const short* __restrict__ xh, const short* __restrict__ xl,
    const short* __restrict__ wh, const short* __restrict__ wl,
    const float* __restrict__ b1, float* __restrict__ h)
{
    __shared__ short Ah[BM4 * BK4], Al[BM4 * BK4];   // 8 KB each
    __shared__ short Bh[BN4 * BK4], Bl[BN4 * BK4];   // 16 KB each -> 48 KB total

    const int t = threadIdx.x;            // 0..511

    // XCD-chunked bijective swizzle (256 blocks % 8 == 0)
    const int lin = blockIdx.y * gridDim.x + blockIdx.x;   // 0..255
    const int cpx = (gridDim.x * gridDim.y) >> 3;          // 32
    const int swz = (lin & 7) * cpx + (lin >> 3);
    const int bm  = (swz >> 2) * BM4;     // consecutive swz share bm -> x reuse in L2
    const int bn  = (swz & 3) * BN4;

    const int wv   = t >> 6;              // 0..7
    const int lane = t & 63;
    const int lm   = lane & 15;
    const int q    = lane >> 4;
    const int wr   = wv >> 2;             // 0..1 : 64-row half
    const int wc   = wv & 3;              // 0..3 : 64-col quarter

    float4v acc[4][4];
    #pragma unroll
    for (int mi = 0; mi < 4; ++mi)
        #pragma unroll
        for (int nj = 0; nj < 4; ++nj) {
            acc[mi][nj][0] = 0.f; acc[mi][nj][1] = 0.f;
            acc[mi][nj][2] = 0.f; acc[mi][nj][3] = 0.f;
        }

    // staging: A one issue (wave covers 16 rows), B two issues (2*128 rows).
    // dest = wave-uniform base + lane*16B: row = (lane>>2), kchunk = lane&3.
    const int srA = wv * 16 + (lane >> 2);          // 0..127
    const int kqq = (lane & 3) * 8;
    const short* gAh = xh + (size_t)(bm + srA) * KP + kqq;
    const short* gAl = xl + (size_t)(bm + srA) * KP + kqq;
    const short* gB0h = wh + (size_t)(bn + srA) * KP + kqq;          // rows 0..127
    const short* gB0l = wl + (size_t)(bn + srA) * KP + kqq;
    const short* gB1h = wh + (size_t)(bn + 128 + srA) * KP + kqq;    // rows 128..255
    const short* gB1l = wl + (size_t)(bn + 128 + srA) * KP + kqq;

    short* lAh = &Ah[wv * 512];
    short* lAl = &Al[wv * 512];
    short* lB0h = &Bh[wv * 512];
    short* lB0l = &Bl[wv * 512];
    short* lB1h = &Bh[4096 + wv * 512];
    short* lB1l = &Bl[4096 + wv * 512];

    // prologue: slab 0 in flight
    gld_lds16(gAh, lAh);   gld_lds16(gAl, lAl);
    gld_lds16(gB0h, lB0h); gld_lds16(gB0l, lB0l);
    gld_lds16(gB1h, lB1h); gld_lds16(gB1l, lB1l);

    for (int it = 0; it < 25; ++it) {
        __syncthreads();   // slab `it` landed for all waves

        short8 fah[4], fal[4];
        #pragma unroll
        for (int mi = 0; mi < 4; ++mi) {
            const int ao = (wr * 64 + mi * 16 + lm) * BK4 + q * 8;
            fah[mi] = *(const short8*)&Ah[ao];
            fal[mi] = *(const short8*)&Al[ao];
        }
        short8 fbh[4], fbl[4];
        #pragma unroll
        for (int nj = 0; nj < 4; ++nj) {
            const int bo = (wc * 64 + nj * 16 + lm) * BK4 + q * 8;
            fbh[nj] = *(const short8*)&Bh[bo];
            fbl[nj] = *(const short8*)&Bl[bo];
        }
        __syncthreads();   // frag reads done; safe to overwrite

        if (it < 24) {     // DMA slab it+1 under the 48 MFMAs
            const int k1 = (it + 1) * BK4;
            gld_lds16(gAh + k1, lAh);   gld_lds16(gAl + k1, lAl);
            gld_lds16(gB0h + k1, lB0h); gld_lds16(gB0l + k1, lB0l);
            gld_lds16(gB1h + k1, lB1h); gld_lds16(gB1l + k1, lB1l);
        }

        #pragma unroll
        for (int nj = 0; nj < 4; ++nj) {
            #pragma unroll
            for (int mi = 0; mi < 4; ++mi) {
                acc[mi][nj] = __builtin_amdgcn_mfma_f32_16x16x32_bf16(fah[mi], fbh[nj], acc[mi][nj], 0, 0, 0);
                acc[mi][nj] = __builtin_amdgcn_mfma_f32_16x16x32_bf16(fah[mi], fbl[nj], acc[mi][nj], 0, 0, 0);
                acc[mi][nj] = __builtin_amdgcn_mfma_f32_16x16x32_bf16(fal[mi], fbh[nj], acc[mi][nj], 0, 0, 0);
            }
        }
    }

    // epilogue: + b1, store fp32. C/D: col = lm, row = q*4 + r.
    #pragma unroll
    for (int mi = 0; mi < 4; ++mi) {
        const int row0 = bm + wr * 64 + mi * 16 + q * 4;
        #pragma unroll
        for (int nj = 0; nj < 4; ++nj) {
            const int col  = bn + wc * 64 + nj * 16 + lm;
            const float bias = b1[col];
            #pragma unroll
            for (int r = 0; r < 4; ++r)
                h[(size_t)(row0 + r) * SYS + col] = acc[mi][nj][r] + bias;
        }
    }
}

// ---------------------------------------------------------------------------
// GEMM1 fallback (in-kernel conversion, 64x64) — only if workspace too small.
// ---------------------------------------------------------------------------
#define BM2 64
#define BN2 64
#define BK2 32
#define LDK2 40

__global__ __launch_bounds__(256, 4) void gemm1_kernel(
    const float* __restrict__ x, const float* __restrict__ W1,
    const float* __restrict__ b1, float* __restrict__ h)
{
    __shared__ short Ah[BM2 * LDK2], Al[BM2 * LDK2];
    __shared__ short Bh[BN2 * LDK2], Bl[BN2 * LDK2];

    const int t  = threadIdx.x;
    const int bm = blockIdx.y * BM2;
    const int bn = blockIdx.x * BN2;

    const int srow = t >> 2;
    const int kq   = (t & 3) * 8;

    const int wv   = t >> 6;
    const int lane = t & 63;
    const int lm   = lane & 15;
    const int q    = lane >> 4;

    float4v acc[4];
    #pragma unroll
    for (int j = 0; j < 4; ++j) {
        acc[j][0] = 0.f; acc[j][1] = 0.f; acc[j][2] = 0.f; acc[j][3] = 0.f;
    }

    const float* xa0 = x  + (size_t)(bm + srow) * INSZ + kq;
    const float* wb0 = W1 + (size_t)(bn + srow) * INSZ + kq;

    for (int it = 0; it < 25; ++it) {
        const int k0 = it * BK2;
        {
            const bool valid = (k0 + kq) < INSZ;
            float va[8], vb[8];
            if (valid) {
                #pragma unroll
                for (int p = 0; p < 2; ++p) {
                    float4 xv = ((const float4*)(xa0 + k0))[p];
                    float4 bv = ((const float4*)(wb0 + k0))[p];
                    va[4*p+0] = xv.x; va[4*p+1] = xv.y; va[4*p+2] = xv.z; va[4*p+3] = xv.w;
                    vb[4*p+0] = bv.x; vb[4*p+1] = bv.y; vb[4*p+2] = bv.z; vb[4*p+3] = bv.w;
                }
            } else {
                #pragma unroll
                for (int j = 0; j < 8; ++j) { va[j] = 0.f; vb[j] = 0.f; }
            }
            short8 ahi, alo, bhi, blo;
            #pragma unroll
            for (int j = 0; j < 8; ++j) {
                short h1 = f2bf(va[j]);
                short l1 = f2bf(va[j] - bf2f(h1));
                short h2 = f2bf(vb[j]);
                short l2 = f2bf(vb[j] - bf2f(h2));
                ahi[j] = h1;  alo[j] = l1;
                bhi[j] = h2;  blo[j] = l2;
            }
            const int base = srow * LDK2 + kq;
            *(short8*)&Ah[base] = ahi;
            *(short8*)&Al[base] = alo;
            *(short8*)&Bh[base] = bhi;
            *(short8*)&Bl[base] = blo;
        }
        __syncthreads();

        const int aoff = (wv * 16 + lm) * LDK2 + q * 8;
        short8 ah = *(const short8*)&Ah[aoff];
        short8 al = *(const short8*)&Al[aoff];
        #pragma unroll
        for (int fj = 0; fj < 4; ++fj) {
            const int boff = (fj * 16 + lm) * LDK2 + q * 8;
            short8 bh = *(const short8*)&Bh[boff];
            short8 bl = *(const short8*)&Bl[boff];
            acc[fj] = __builtin_amdgcn_mfma_f32_16x16x32_bf16(ah, bh, acc[fj], 0, 0, 0);
            acc[fj] = __builtin_amdgcn_mfma_f32_16x16x32_bf16(ah, bl, acc[fj], 0, 0, 0);
            acc[fj] = __builtin_amdgcn_mfma_f32_16x16x32_bf16(al, bh, acc[fj], 0, 0, 0);
        }
        __syncthreads();
    }

    #pragma unroll
    for (int fj = 0; fj < 4; ++fj) {
        const int col  = bn + fj * 16 + lm;
        const float bias = b1[col];
        const int row0 = bm + wv * 16 + q * 4;
        #pragma unroll
        for (int r = 0; r < 4; ++r)
            h[(size_t)(row0 + r) * SYS + col] = acc[fj][r] + bias;
    }
}

// ---------------------------------------------------------------------------
// RK4 Lorenz-96 + GEMM2 + log_softmax — r3 v2f version VERBATIM (measured
// 296-304 us plateau; VALUBusy ~80%, VGPR 64 + AGPR parking).
// r4 lesson: do NOT force 8 waves/SIMD — the 64-VGPR cap spills the 48-float
// state to scratch (VGPR_Count=32, 21.7 GB scratch traffic, 15x slowdown).
// The v2f/AGPR layout at 4 waves/SIMD IS the right operating point.
// ---------------------------------------------------------------------------
__global__ __launch_bounds__(256, 4) void rk4_kernel(
    const float* __restrict__ hbuf, const float* __restrict__ W2,
    const float* __restrict__ b2, float* __restrict__ out)
{
    const int lane = threadIdx.x & 63;
    const int w    = threadIdx.x >> 6;
    const int rowA = blockIdx.x * 8 + w * 2;
    const int rowB = rowA + 1;

    const int laneL = (lane + 63) & 63;
    const int laneR = (lane + 1) & 63;

    v2f X[16];
    {
        const float4* a4 = (const float4*)(hbuf + (size_t)rowA * SYS) + lane * 4;
        const float4* b4 = (const float4*)(hbuf + (size_t)rowB * SYS) + lane * 4;
        #pragma unroll
        for (int k = 0; k < 4; ++k) {
            float4 av = a4[k], bv = b4[k];
            X[4*k+0] = mk2(av.x, bv.x);
            X[4*k+1] = mk2(av.y, bv.y);
            X[4*k+2] = mk2(av.z, bv.z);
            X[4*k+3] = mk2(av.w, bv.w);
        }
    }

    const v2f Fv     = mk2(FFORCE, FFORCE);
    const v2f c_half = mk2(0.5f * HSTEP, 0.5f * HSTEP);
    const v2f c_full = mk2(HSTEP, HSTEP);
    const v2f c_two  = mk2(2.0f, 2.0f);
    const v2f c_six  = mk2(HSTEP / 6.0f, HSTEP / 6.0f);

    v2f acc[16], T[16];

    auto deriv_ip = [&](v2f (&y)[16], v2f r1, v2f l1, v2f l2) {
        v2f y0o = y[0], y1o = y[1], y2o = y[2];
        v2f d0 = Fv - y[0], d1 = Fv - y[1], d15 = Fv - y[15];
        v2f p2 = y0o, p1 = y1o, cur = y[2];
        #pragma unroll
        for (int i = 2; i < 15; ++i) {
            v2f yp1 = (i < 14) ? y[i + 1] : y[15];
            v2f nv  = pkfma(yp1 - p2, p1, Fv - cur);
            p2 = p1; p1 = cur;
            if (i < 14) cur = y[i + 1];
            y[i] = nv;
        }
        y[15] = pkfma(r1 - p2, p1, d15);
        y[1]  = pkfma(y2o - l1, y0o, d1);
        y[0]  = pkfma(y1o - l2, l1, d0);
    };

    v2f r1x = sh2(X[0],  laneR);
    v2f l1x = sh2(X[15], laneL);
    v2f l2x = sh2(X[14], laneL);

    #pragma unroll 1
    for (int s = 0; s < NSTEP; ++s) {
        #pragma unroll
        for (int i = 2; i < 15; ++i)
            acc[i] = pkfma(X[i + 1] - X[i - 2], X[i - 1], Fv - X[i]);
        acc[15] = pkfma(r1x - X[13], X[14], Fv - X[15]);
        acc[1]  = pkfma(X[2] - l1x, X[0],  Fv - X[1]);
        acc[0]  = pkfma(X[1] - l2x, l1x,   Fv - X[0]);

        T[14] = pkfma(c_half, acc[14], X[14]);
        T[15] = pkfma(c_half, acc[15], X[15]);
        T[0]  = pkfma(c_half, acc[0],  X[0]);
        v2f r1 = sh2(T[0],  laneR);
        v2f l1 = sh2(T[15], laneL);
        v2f l2 = sh2(T[14], laneL);
        #pragma unroll
        for (int i = 1; i < 14; ++i) T[i] = pkfma(c_half, acc[i], X[i]);
        deriv_ip(T, r1, l1, l2);

        {
            v2f a;
            a = T[14]; acc[14] = pkfma(c_two, a, acc[14]); T[14] = pkfma(c_half, a, X[14]);
            a = T[15]; acc[15] = pkfma(c_two, a, acc[15]); T[15] = pkfma(c_half, a, X[15]);
            a = T[0];  acc[0]  = pkfma(c_two, a, acc[0]);  T[0]  = pkfma(c_half, a, X[0]);
            r1 = sh2(T[0],  laneR);
            l1 = sh2(T[15], laneL);
            l2 = sh2(T[14], laneL);
            #pragma unroll
            for (int i = 1; i < 14; ++i) {
                a = T[i]; acc[i] = pkfma(c_two, a, acc[i]); T[i] = pkfma(c_half, a, X[i]);
            }
        }
        deriv_ip(T, r1, l1, l2);

        {
            v2f a;
            a = T[14]; acc[14] = pkfma(c_two, a, acc[14]); T[14] = pkfma(c_full, a, X[14]);
            a = T[15]; acc[15] = pkfma(c_two, a, acc[15]); T[15] = pkfma(c_full, a, X[15]);
            a = T[0];  acc[0]  = pkfma(c_two, a, acc[0]);  T[0]  = pkfma(c_full, a, X[0]);
            r1 = sh2(T[0],  laneR);
            l1 = sh2(T[15], laneL);
            l2 = sh2(T[14], laneL);
            #pragma unroll
            for (int i = 1; i < 14; ++i) {
                a = T[i]; acc[i] = pkfma(c_two, a, acc[i]); T[i] = pkfma(c_full, a, X[i]);
            }
        }
        deriv_ip(T, r1, l1, l2);

        X[14] = pkfma(c_six, acc[14] + T[14], X[14]);
        X[15] = pkfma(c_six, acc[15] + T[15], X[15]);
        X[0]  = pkfma(c_six, acc[0]  + T[0],  X[0]);
        r1x = sh2(X[0],  laneR);
        l1x = sh2(X[15], laneL);
        l2x = sh2(X[14], laneL);
        #pragma unroll
        for (int i = 1; i < 14; ++i)
            X[i] = pkfma(c_six, acc[i] + T[i], X[i]);
    }

    v2f l[OUTSZ];
    #pragma unroll
    for (int o = 0; o < OUTSZ; ++o) {
        const float4* w4 = (const float4*)(W2 + (size_t)o * SYS) + lane * 4;
        v2f s2 = mk2(0.f, 0.f);
        #pragma unroll
        for (int k = 0; k < 4; ++k) {
            float4 wv = w4[k];
            s2 = pkfma(X[4*k+0], mk2(wv.x, wv.x), s2);
            s2 = pkfma(X[4*k+1], mk2(wv.y, wv.y), s2);
            s2 = pkfma(X[4*k+2], mk2(wv.z, wv.z), s2);
            s2 = pkfma(X[4*k+3], mk2(wv.w, wv.w), s2);
        }
        #pragma unroll
        for (int dlt = 1; dlt < 64; dlt <<= 1) {
            s2.x += __shfl_xor(s2.x, dlt);
            s2.y += __shfl_xor(s2.y, dlt);
        }
        const float bo = b2[o];
        l[o] = s2 + mk2(bo, bo);
    }

    v2f m = l[0];
    #pragma unroll
    for (int o = 1; o < OUTSZ; ++o) m = __builtin_elementwise_max(m, l[o]);
    v2f ssum = mk2(0.f, 0.f);
    #pragma unroll
    for (int o = 0; o < OUTSZ; ++o) {
        v2f d = l[o] - m;
        ssum = ssum + mk2(__expf(d.x), __expf(d.y));
    }
    const v2f lse = m + mk2(__logf(ssum.x), __logf(ssum.y));

    float vA = l[0].x - lse.x;
    float vB = l[0].y - lse.y;
    #pragma unroll
    for (int o = 1; o < OUTSZ; ++o) {
        if (lane == o) { vA = l[o].x - lse.x; vB = l[o].y - lse.y; }
    }
    if (lane < OUTSZ) {
        out[(size_t)rowA * OUTSZ + lane] = vA;
        out[(size_t)rowB * OUTSZ + lane] = vB;
    }
}

extern "C" void kernel_launch(void* const* d_in, const int* in_sizes, int n_in,
                              void* d_out, int out_size, void* d_ws, size_t ws_size,
                              hipStream_t stream)
{
    const float* x  = (const float*)d_in[0];
    const float* W1 = (const float*)d_in[1];
    const float* b1 = (const float*)d_in[2];
    const float* W2 = (const float*)d_in[3];
    const float* b2 = (const float*)d_in[4];
    float* out = (float*)d_out;
    float* h   = (float*)d_ws;   // 8192*1024*4 = 33.5 MB scratch

    const size_t hbytes      = (size_t)BATCH * SYS * sizeof(float);
    const size_t splitshorts = (size_t)(BATCH + SYS) * KP;           // per hi/lo member
    const size_t need        = hbytes + 2 * splitshorts * sizeof(short);

    if (ws_size >= need) {
        short* xh = (short*)((char*)d_ws + hbytes);
        short* xl = xh + (size_t)BATCH * KP;
        short* wh = xl + (size_t)BATCH * KP;
        short* wl = wh + (size_t)SYS * KP;
        convert_kernel<<<2048, 256, 0, stream>>>(x, W1, xh, xl, wh, wl);
        dim3 g1(SYS / BN4, BATCH / BM4);   // 4 x 64 = 256 blocks, 512 threads
        gemm1s_kernel<<<g1, 512, 0, stream>>>(xh, xl, wh, wl, b1, h);
    } else {
        dim3 g1(SYS / BN2, BATCH / BM2);   // fallback: 16 x 128 = 2048 blocks
        gemm1_kernel<<<g1, 256, 0, stream>>>(x, W1, b1, h);
    }

    rk4_kernel<<<BATCH / 8, 256, 0, stream>>>(h, W2, b2, out);  // 1024 blocks, 2 rows/wave
}